// Round 1
// baseline (323.971 us; speedup 1.0000x reference)
//
#include <hip/hip_runtime.h>
#include <math.h>

// Problem constants (fixed by reference): B=4, C=64, pooled 32^3, out 64^3.
#define NBC   256      // B*C
#define SP    32768    // 32^3 pooled elements per (b,c)
#define SO    262144   // 64^3 output elements per (b,c)

// Pass 1: per-(b,c) channel gating = log_sigmoid( sum(silu(pooled)) / SO ).
// One block per (b,c), 256 threads, float4 loads (32 per thread).
__global__ __launch_bounds__(256) void gate_kernel(
    const float* __restrict__ pooled, float* __restrict__ gate)
{
    const int bc = blockIdx.x;
    const int t  = threadIdx.x;
    const float4* p4 = (const float4*)(pooled + (size_t)bc * SP);

    float s = 0.f;
    #pragma unroll 8
    for (int i = 0; i < 32; ++i) {
        float4 v = p4[i * 256 + t];
        s += v.x / (1.f + expf(-v.x));
        s += v.y / (1.f + expf(-v.y));
        s += v.z / (1.f + expf(-v.z));
        s += v.w / (1.f + expf(-v.w));
    }
    // wave64 reduce
    #pragma unroll
    for (int off = 32; off > 0; off >>= 1)
        s += __shfl_down(s, off, 64);

    __shared__ float ls[4];
    if ((t & 63) == 0) ls[t >> 6] = s;
    __syncthreads();
    if (t == 0) {
        float tot = ls[0] + ls[1] + ls[2] + ls[3];
        float m = tot / (float)SO;
        // stable log-sigmoid
        float g = (m >= 0.f) ? -log1pf(expf(-m)) : m - log1pf(expf(m));
        gate[bc] = g;
    }
}

// Pass 2: gather-style unpool+gate. Each thread owns 2 adjacent pooled
// windows along w' (their indices are contiguous: window linear = 2p, 2p+1)
// and writes the corresponding 2x2x2 output blocks as 4 coalesced float4s.
// Index parity bits select the hot slot: d=idx>>12, h=(idx>>6)&63, w=idx&63;
// window guarantees d=2d'+od etc., so od=(idx>>12)&1, oh=(idx>>6)&1, ow=idx&1.
__global__ __launch_bounds__(256) void unpool_kernel(
    const float* __restrict__ pooled, const int* __restrict__ idx,
    const float* __restrict__ gate, float* __restrict__ out)
{
    const int bc = blockIdx.x >> 6;                       // 64 blocks per (b,c)
    const int p  = ((blockIdx.x & 63) << 8) | threadIdx.x; // pair index [0,16384)

    const size_t sbase = (size_t)bc * SP + 2 * (size_t)p;
    const float2 v  = *(const float2*)(pooled + sbase);
    const int2   ix = *(const int2*)(idx + sbase);
    const float  g  = gate[bc];

    const float gv0 = g * v.x;
    const float gv1 = g * v.y;

    // 3-bit slot code: od*4 + oh*2 + ow
    const int c0 = (((ix.x >> 12) & 1) << 2) | (((ix.x >> 6) & 1) << 1) | (ix.x & 1);
    const int c1 = (((ix.y >> 12) & 1) << 2) | (((ix.y >> 6) & 1) << 1) | (ix.y & 1);

    // p = d'*512 + h'*16 + wp  (wp in [0,16), covers w'=2wp, 2wp+1)
    const int dp = p >> 9;
    const int hp = (p >> 4) & 31;
    const int wp = p & 15;

    float* ob = out + (size_t)bc * SO
                    + (size_t)(dp * 2) * 4096   // d stride = 64*64
                    + (hp * 2) * 64             // h stride = 64
                    + wp * 4;                   // w = 4*wp .. 4*wp+3

    #pragma unroll
    for (int rr = 0; rr < 2; ++rr) {
        #pragma unroll
        for (int cc = 0; cc < 2; ++cc) {
            const int s0 = (rr << 2) | (cc << 1);
            float4 f;
            f.x = (c0 == s0)       ? gv0 : 0.f;
            f.y = (c0 == (s0 | 1)) ? gv0 : 0.f;
            f.z = (c1 == s0)       ? gv1 : 0.f;
            f.w = (c1 == (s0 | 1)) ? gv1 : 0.f;
            *(float4*)(ob + rr * 4096 + cc * 64) = f;
        }
    }
}

extern "C" void kernel_launch(void* const* d_in, const int* in_sizes, int n_in,
                              void* d_out, int out_size, void* d_ws, size_t ws_size,
                              hipStream_t stream) {
    const float* pooled = (const float*)d_in[0];
    const int*   indices = (const int*)d_in[1];
    float*       out  = (float*)d_out;
    float*       gate = (float*)d_ws;   // 256 floats of scratch

    gate_kernel<<<NBC, 256, 0, stream>>>(pooled, gate);
    unpool_kernel<<<NBC * 64, 256, 0, stream>>>(pooled, indices, gate, out);
}

// Round 2
// 319.270 us; speedup vs baseline: 1.0147x; 1.0147x over previous
//
#include <hip/hip_runtime.h>
#include <math.h>

// Problem constants (fixed by reference): B=4, C=64, pooled 32^3, out 64^3.
#define NBC   256      // B*C
#define SP    32768    // 32^3 pooled elements per (b,c)
#define SO    262144   // 64^3 output elements per (b,c)
#define PARTS 8        // partial-sum blocks per channel

// Pass 1: partial silu-sums per (b,c). 2048 blocks (= 256 channels x 8 parts),
// 256 threads, 4 independent float4 loads per thread -> latency-hidden.
// No atomics / no zero-init: every partial slot is written exactly once.
__global__ __launch_bounds__(256) void gate_partial_kernel(
    const float* __restrict__ pooled, float* __restrict__ partial)
{
    const int blk  = blockIdx.x;          // bc*PARTS + part
    const int bc   = blk >> 3;
    const int part = blk & 7;
    const int t    = threadIdx.x;

    const float4* p4 = (const float4*)(pooled + (size_t)bc * SP) + part * 1024;

    float4 v0 = p4[0 * 256 + t];
    float4 v1 = p4[1 * 256 + t];
    float4 v2 = p4[2 * 256 + t];
    float4 v3 = p4[3 * 256 + t];

    float s = 0.f;
    s += v0.x / (1.f + __expf(-v0.x)) + v0.y / (1.f + __expf(-v0.y))
       + v0.z / (1.f + __expf(-v0.z)) + v0.w / (1.f + __expf(-v0.w));
    s += v1.x / (1.f + __expf(-v1.x)) + v1.y / (1.f + __expf(-v1.y))
       + v1.z / (1.f + __expf(-v1.z)) + v1.w / (1.f + __expf(-v1.w));
    s += v2.x / (1.f + __expf(-v2.x)) + v2.y / (1.f + __expf(-v2.y))
       + v2.z / (1.f + __expf(-v2.z)) + v2.w / (1.f + __expf(-v2.w));
    s += v3.x / (1.f + __expf(-v3.x)) + v3.y / (1.f + __expf(-v3.y))
       + v3.z / (1.f + __expf(-v3.z)) + v3.w / (1.f + __expf(-v3.w));

    // wave64 reduce
    #pragma unroll
    for (int off = 32; off > 0; off >>= 1)
        s += __shfl_down(s, off, 64);

    __shared__ float ls[4];
    if ((t & 63) == 0) ls[t >> 6] = s;
    __syncthreads();
    if (t == 0) partial[blk] = ls[0] + ls[1] + ls[2] + ls[3];
}

// Pass 2: gather-style unpool+gate. Each thread owns 2 adjacent pooled
// windows along w' and writes the corresponding 2x2x2 output blocks as
// 4 coalesced float4s (each 16-lane group fills a full 64-float w row).
// Index parity bits select the hot slot inside each 2x2x2 window.
__global__ __launch_bounds__(256) void unpool_kernel(
    const float* __restrict__ pooled, const int* __restrict__ idx,
    const float* __restrict__ partial, float* __restrict__ out)
{
    const int bc = blockIdx.x >> 6;                        // 64 blocks per (b,c)
    const int p  = ((blockIdx.x & 63) << 8) | threadIdx.x; // pair index [0,16384)

    // finish the channel reduction (block-uniform -> scalar loads)
    const float* pp = partial + bc * PARTS;
    float tot = 0.f;
    #pragma unroll
    for (int i = 0; i < PARTS; ++i) tot += pp[i];
    const float m = tot * (1.f / (float)SO);
    const float g = (m >= 0.f) ? -log1pf(__expf(-m)) : m - log1pf(__expf(m));

    const size_t sbase = (size_t)bc * SP + 2 * (size_t)p;
    const float2 v  = *(const float2*)(pooled + sbase);
    const int2   ix = *(const int2*)(idx + sbase);

    const float gv0 = g * v.x;
    const float gv1 = g * v.y;

    // 3-bit slot code: od*4 + oh*2 + ow
    const int c0 = (((ix.x >> 12) & 1) << 2) | (((ix.x >> 6) & 1) << 1) | (ix.x & 1);
    const int c1 = (((ix.y >> 12) & 1) << 2) | (((ix.y >> 6) & 1) << 1) | (ix.y & 1);

    // p = d'*512 + h'*16 + wp  (wp in [0,16), covers w'=2wp, 2wp+1)
    const int dp = p >> 9;
    const int hp = (p >> 4) & 31;
    const int wp = p & 15;

    float* ob = out + (size_t)bc * SO
                    + (size_t)(dp * 2) * 4096   // d stride = 64*64
                    + (hp * 2) * 64             // h stride = 64
                    + wp * 4;                   // w = 4*wp .. 4*wp+3

    #pragma unroll
    for (int rr = 0; rr < 2; ++rr) {
        #pragma unroll
        for (int cc = 0; cc < 2; ++cc) {
            const int s0 = (rr << 2) | (cc << 1);
            float4 f;
            f.x = (c0 == s0)       ? gv0 : 0.f;
            f.y = (c0 == (s0 | 1)) ? gv0 : 0.f;
            f.z = (c1 == s0)       ? gv1 : 0.f;
            f.w = (c1 == (s0 | 1)) ? gv1 : 0.f;
            *(float4*)(ob + rr * 4096 + cc * 64) = f;
        }
    }
}

extern "C" void kernel_launch(void* const* d_in, const int* in_sizes, int n_in,
                              void* d_out, int out_size, void* d_ws, size_t ws_size,
                              hipStream_t stream) {
    const float* pooled  = (const float*)d_in[0];
    const int*   indices = (const int*)d_in[1];
    float*       out     = (float*)d_out;
    float*       partial = (float*)d_ws;   // NBC*PARTS floats of scratch

    gate_partial_kernel<<<NBC * PARTS, 256, 0, stream>>>(pooled, partial);
    unpool_kernel<<<NBC * 64, 256, 0, stream>>>(pooled, indices, partial, out);
}